// Round 5
// baseline (582.471 us; speedup 1.0000x reference)
//
#include <hip/hip_runtime.h>

#define THREADS 256
#define EPT 2   // edges per thread

typedef float f32x4 __attribute__((ext_vector_type(4)));
typedef int   i32x2 __attribute__((ext_vector_type(2)));

// feat layout per edge: x_s[0..10) | x_t[10..15) | edge_attr[15..25) | u[25..35)
// d_in = 35, F_OUT = 5

// launch_bounds: 2nd arg is min waves per EU (SIMD). 8 waves/EU * 4 EU = 32
// waves/CU = 100% occupancy target; requires VGPR<=64 (compiler hit exactly
// 64 last round with the same body).
__global__ __launch_bounds__(THREADS, 8) void edge_model_kernel(
    const float* __restrict__ x_s,      // [N_S,10]
    const float* __restrict__ x_t,      // [N_T,5]
    const int* __restrict__ edge_index, // [2,E]
    const float* __restrict__ edge_attr,// [E,10]
    const float* __restrict__ u,        // [64,10]
    const int* __restrict__ batch_e,    // [E]
    const float* __restrict__ W1,       // [35,5]
    const float* __restrict__ b1,       // [5]
    const float* __restrict__ W2,       // [5,5]
    const float* __restrict__ b2,       // [5]
    float* __restrict__ out,            // [E,5]
    int E)
{
    __shared__ float sW1[35 * 5];
    __shared__ float sb1[5];
    __shared__ float sW2[5 * 5];
    __shared__ float sb2[5];
    __shared__ float su[64 * 11];             // stride 11: coprime with 32 banks
    __shared__ float sout[THREADS * 5 * EPT]; // staged output, 10 KB

    const int t = threadIdx.x;

    for (int i = t; i < 35 * 5; i += THREADS) sW1[i] = W1[i];
    if (t < 5)  sb1[t] = b1[t];
    if (t < 25) sW2[t] = W2[t];
    if (t >= 32 && t < 37) sb2[t - 32] = b2[t - 32];
    for (int i = t; i < 64 * 10; i += THREADS) {
        int r = i / 10, c = i - r * 10;
        su[r * 11 + c] = u[i];
    }
    __syncthreads();

    const int e0 = (blockIdx.x * THREADS + t) * EPT;

    if (e0 + EPT <= E) {
        // ---------- fast path: 2 edges / thread ----------
        int src[EPT], tgt[EPT], bb[EPT];
        {
            i32x2 v = *reinterpret_cast<const i32x2*>(edge_index + e0);
            src[0] = v.x; src[1] = v.y;
        }
        if ((E & 1) == 0) {   // uniform branch
            i32x2 v = *reinterpret_cast<const i32x2*>(edge_index + E + e0);
            tgt[0] = v.x; tgt[1] = v.y;
        } else {
            tgt[0] = edge_index[E + e0];
            tgt[1] = edge_index[E + e0 + 1];
        }
        {
            i32x2 v = *reinterpret_cast<const i32x2*>(batch_e + e0);
            bb[0] = v.x; bb[1] = v.y;
        }

        // streamed edge_attr: 2 rows = 80 B contiguous, 16B-aligned.
        // NORMAL loads (not nt): the 5 instructions covering each 64B line
        // must merge in L2; nt-bypass inflated FETCH by ~160 MB last round.
        float eav[20];
        {
            const f32x4* ea4 = reinterpret_cast<const f32x4*>(edge_attr + (size_t)e0 * 10);
            #pragma unroll
            for (int i = 0; i < 5; ++i) {
                f32x4 v = ea4[i];
                eav[4 * i]     = v.x;
                eav[4 * i + 1] = v.y;
                eav[4 * i + 2] = v.z;
                eav[4 * i + 3] = v.w;
            }
        }

        // gathers: 10 float2 + 10 scalar in flight
        float2 xs[EPT][5];
        float  xt[EPT][5];
        #pragma unroll
        for (int k = 0; k < EPT; ++k) {
            const float2* p = reinterpret_cast<const float2*>(x_s + (size_t)src[k] * 10);
            #pragma unroll
            for (int i = 0; i < 5; ++i) xs[k][i] = p[i];
        }
        #pragma unroll
        for (int k = 0; k < EPT; ++k) {
            const float* p = x_t + (size_t)tgt[k] * 5;
            #pragma unroll
            for (int i = 0; i < 5; ++i) xt[k][i] = p[i];
        }

        #pragma unroll
        for (int k = 0; k < EPT; ++k) {
            float feat[35];
            #pragma unroll
            for (int i = 0; i < 5; ++i) {
                feat[2 * i]     = xs[k][i].x;
                feat[2 * i + 1] = xs[k][i].y;
            }
            #pragma unroll
            for (int i = 0; i < 5; ++i) feat[10 + i] = xt[k][i];
            #pragma unroll
            for (int i = 0; i < 10; ++i) feat[15 + i] = eav[k * 10 + i];
            #pragma unroll
            for (int i = 0; i < 10; ++i) feat[25 + i] = su[bb[k] * 11 + i];

            float h[5];
            #pragma unroll
            for (int j = 0; j < 5; ++j) {
                float acc = sb1[j];
                #pragma unroll
                for (int kk = 0; kk < 35; ++kk) acc = fmaf(feat[kk], sW1[kk * 5 + j], acc);
                h[j] = (acc > 0.0f) ? acc : 0.1f * acc;
            }
            #pragma unroll
            for (int j = 0; j < 5; ++j) {
                float acc = sb2[j];
                #pragma unroll
                for (int i = 0; i < 5; ++i) acc = fmaf(h[i], sW2[i * 5 + j], acc);
                sout[t * (5 * EPT) + k * 5 + j] = acc;
            }
        }
    } else {
        // ---------- tail path: per-edge scalar, staged to LDS too ----------
        for (int e = e0; e < min(e0 + EPT, E); ++e) {
            const int s  = edge_index[e];
            const int tg = edge_index[E + e];
            const int b  = batch_e[e];
            float feat[35];
            #pragma unroll
            for (int i = 0; i < 10; ++i) feat[i]      = x_s[(size_t)s * 10 + i];
            #pragma unroll
            for (int i = 0; i < 5; ++i)  feat[10 + i] = x_t[(size_t)tg * 5 + i];
            #pragma unroll
            for (int i = 0; i < 10; ++i) feat[15 + i] = edge_attr[(size_t)e * 10 + i];
            #pragma unroll
            for (int i = 0; i < 10; ++i) feat[25 + i] = su[b * 11 + i];
            float h[5];
            #pragma unroll
            for (int j = 0; j < 5; ++j) {
                float acc = sb1[j];
                #pragma unroll
                for (int kk = 0; kk < 35; ++kk) acc = fmaf(feat[kk], sW1[kk * 5 + j], acc);
                h[j] = (acc > 0.0f) ? acc : 0.1f * acc;
            }
            #pragma unroll
            for (int j = 0; j < 5; ++j) {
                float acc = sb2[j];
                #pragma unroll
                for (int i = 0; i < 5; ++i) acc = fmaf(h[i], sW2[i * 5 + j], acc);
                sout[t * (5 * EPT) + (e - e0) * 5 + j] = acc;
            }
        }
    }
    __syncthreads();

    // coalesced copy-out: each instruction writes 256 consecutive dwords
    // (1 KB, full lines) -> nt store safe (no RMW) and keeps the 80 MB
    // output stream out of L2, protecting x_s/x_t residency.
    const size_t base  = (size_t)blockIdx.x * THREADS * 5 * EPT;
    const int    nval  = min(THREADS * EPT, E - blockIdx.x * THREADS * EPT);
    const int    nflt  = nval * 5;
    for (int i = t; i < nflt; i += THREADS)
        __builtin_nontemporal_store(sout[i], out + base + i);
}

extern "C" void kernel_launch(void* const* d_in, const int* in_sizes, int n_in,
                              void* d_out, int out_size, void* d_ws, size_t ws_size,
                              hipStream_t stream)
{
    const float* x_s       = (const float*)d_in[0];
    const float* x_t       = (const float*)d_in[1];
    const int*   edge_idx  = (const int*)  d_in[2];
    const float* edge_attr = (const float*)d_in[3];
    const float* u         = (const float*)d_in[4];
    const int*   batch_e   = (const int*)  d_in[5];
    const float* W1        = (const float*)d_in[6];
    const float* b1        = (const float*)d_in[7];
    const float* W2        = (const float*)d_in[8];
    const float* b2        = (const float*)d_in[9];
    float*       out       = (float*)d_out;

    const int E = in_sizes[5];  // batch_e has E elements

    const int edges_per_block = THREADS * EPT;
    const int grid = (E + edges_per_block - 1) / edges_per_block;
    edge_model_kernel<<<grid, THREADS, 0, stream>>>(
        x_s, x_t, edge_idx, edge_attr, u, batch_e, W1, b1, W2, b2, out, E);
}

// Round 6
// 411.468 us; speedup vs baseline: 1.4156x; 1.4156x over previous
//
#include <hip/hip_runtime.h>

#define THREADS 256
#define EPB 256      // edges per block
#define FSTRIDE 27   // 25 feat floats + 2 pad; 27 coprime with 32 banks

// feat columns: x_s[0..10) | x_t[10..15) | edge_attr[15..25); u applied from su
// W1 rows: x_s 0..10, x_t 10..15, ea 15..25, u 25..35.  d_in=35, F_OUT=5

__global__ __launch_bounds__(THREADS, 4) void edge_model_kernel(
    const float* __restrict__ x_s,      // [N_S,10]
    const float* __restrict__ x_t,      // [N_T,5]
    const int* __restrict__ edge_index, // [2,E]
    const float* __restrict__ edge_attr,// [E,10]
    const float* __restrict__ u,        // [64,10]
    const int* __restrict__ batch_e,    // [E]
    const float* __restrict__ W1,       // [35,5]
    const float* __restrict__ b1,       // [5]
    const float* __restrict__ W2,       // [5,5]
    const float* __restrict__ b2,       // [5]
    float* __restrict__ out,            // [E,5]
    int E)
{
    __shared__ float sW1[35 * 5];
    __shared__ float sb1[5];
    __shared__ float sW2[25];
    __shared__ float sb2[5];
    __shared__ float su[64 * 11];       // stride 11 coprime w/ 32
    __shared__ int   ssrc[EPB];
    __shared__ int   stgt[EPB];
    __shared__ float sfeat[EPB * FSTRIDE]; // 27.6 KB
    __shared__ float sout[EPB * 5];        // 5 KB

    const int t    = threadIdx.x;
    const int base = blockIdx.x * EPB;
    const int nval = min(EPB, E - base);

    // ---- stage weights + u (broadcast tables) ----
    for (int i = t; i < 35 * 5; i += THREADS) sW1[i] = W1[i];
    if (t < 5)  sb1[t] = b1[t];
    if (t < 25) sW2[t] = W2[t];
    if (t >= 32 && t < 37) sb2[t - 32] = b2[t - 32];
    for (int i = t; i < 64 * 10; i += THREADS) {
        int r = i / 10, c = i - r * 10;
        su[r * 11 + c] = u[i];
    }

    // ---- stage this block's indices (coalesced) ----
    int myb = 0;
    if (t < nval) {
        ssrc[t] = edge_index[base + t];
        stgt[t] = edge_index[(size_t)E + base + t];
        myb     = batch_e[base + t];
    }
    __syncthreads();

    // ---- cooperative gathers: consecutive lanes -> consecutive elements of
    // the same row, so one wave instruction touches ~10 lines, not 64 ----

    // x_s rows -> sfeat[e][0..10)
    {
        const int tot = nval * 10;
        for (int i = t; i < tot; i += THREADS) {
            int e = i / 10, c = i - e * 10;        // magic-mul, cheap
            sfeat[e * FSTRIDE + c] = x_s[(size_t)ssrc[e] * 10 + c];
        }
    }
    // x_t rows -> sfeat[e][10..15)
    {
        const int tot = nval * 5;
        for (int i = t; i < tot; i += THREADS) {
            int e = i / 5, c = i - e * 5;
            sfeat[e * FSTRIDE + 10 + c] = x_t[(size_t)stgt[e] * 5 + c];
        }
    }
    // edge_attr -> sfeat[e][15..25)   (perfectly contiguous stream)
    {
        const int tot = nval * 10;
        const float* ea = edge_attr + (size_t)base * 10;
        for (int i = t; i < tot; i += THREADS) {
            int e = i / 10, c = i - e * 10;
            sfeat[e * FSTRIDE + 15 + c] = ea[i];
        }
    }
    __syncthreads();

    // ---- compute: one edge per thread, feat streamed from LDS ----
    if (t < nval) {
        const float* f  = &sfeat[t * FSTRIDE];   // stride 27: conflict-free
        const float* uu = &su[myb * 11];

        float h[5];
        #pragma unroll
        for (int j = 0; j < 5; ++j) h[j] = sb1[j];
        #pragma unroll
        for (int k = 0; k < 25; ++k) {
            float v = f[k];
            #pragma unroll
            for (int j = 0; j < 5; ++j) h[j] = fmaf(v, sW1[k * 5 + j], h[j]);
        }
        #pragma unroll
        for (int k = 0; k < 10; ++k) {
            float v = uu[k];
            #pragma unroll
            for (int j = 0; j < 5; ++j) h[j] = fmaf(v, sW1[(25 + k) * 5 + j], h[j]);
        }
        #pragma unroll
        for (int j = 0; j < 5; ++j) h[j] = (h[j] > 0.0f) ? h[j] : 0.1f * h[j];

        #pragma unroll
        for (int j = 0; j < 5; ++j) {
            float acc = sb2[j];
            #pragma unroll
            for (int i2 = 0; i2 < 5; ++i2) acc = fmaf(h[i2], sW2[i2 * 5 + j], acc);
            sout[t * 5 + j] = acc;
        }
    }
    __syncthreads();

    // ---- coalesced nt copy-out: full contiguous lines, no RMW,
    // keeps the 80 MB output stream out of L2 ----
    const int nflt = nval * 5;
    float* ob = out + (size_t)base * 5;
    for (int i = t; i < nflt; i += THREADS)
        __builtin_nontemporal_store(sout[i], ob + i);
}

extern "C" void kernel_launch(void* const* d_in, const int* in_sizes, int n_in,
                              void* d_out, int out_size, void* d_ws, size_t ws_size,
                              hipStream_t stream)
{
    const float* x_s       = (const float*)d_in[0];
    const float* x_t       = (const float*)d_in[1];
    const int*   edge_idx  = (const int*)  d_in[2];
    const float* edge_attr = (const float*)d_in[3];
    const float* u         = (const float*)d_in[4];
    const int*   batch_e   = (const int*)  d_in[5];
    const float* W1        = (const float*)d_in[6];
    const float* b1        = (const float*)d_in[7];
    const float* W2        = (const float*)d_in[8];
    const float* b2        = (const float*)d_in[9];
    float*       out       = (float*)d_out;

    const int E = in_sizes[5];  // batch_e has E elements

    const int grid = (E + EPB - 1) / EPB;
    edge_model_kernel<<<grid, THREADS, 0, stream>>>(
        x_s, x_t, edge_idx, edge_attr, u, batch_e, W1, b1, W2, b2, out, E);
}